// Round 1
// baseline (68.711 us; speedup 1.0000x reference)
//
#include <hip/hip_runtime.h>
#include <math.h>

// TropConv2D: out[b,i,j,f] = max_k(p[k]+w[k,f]) - min_k(p[k]+w[k,f]) + bias[f]
// k = (ki*3+kj)*32+c, 3x3 window, C=32, F=64.
// x: [8,32,32,32] f32, w: [288,64] f32, bias: [64] f32, out: [8,30,30,64] f32.
//
// R9 = 8-col waves + multi-block-per-CU overlap:
//  - grid (30,8,2): z splits the 30 output cols into [0,16) / [16,30).
//    480 blocks x 256 thr, 49.5 KB LDS, launch_bounds(256,3) -> 3 blocks/CU
//    co-resident: one block's global->LDS staging overlaps others' compute
//    (R8 had exactly 1 block/CU: stage->barrier->compute fully serial).
//  - wave = 8 output cols x 64 filters x 16 channels (2-way channel split).
//    Per (ki,c8) step: 13 ds_read_b128 (10 x-broadcast + 3 w) feed 96 packed
//    taps vs 9:48 in R8 -> per-CU LDS-issue (the binding pipe: 10.4K cyc/CU
//    vs 6.9K VALU/SIMD in R8) drops ~28%.
//  - merge buffer shrinks 16 KB -> 8 KB, layout [pair][mx/mn][half][f]
//    (lane-consecutive b128, conflict-free).

typedef _Float16 half2v __attribute__((ext_vector_type(2)));
typedef _Float16 half8v __attribute__((ext_vector_type(8)));

#define WSTRIDE 296  // halves; 592 B rows = 148 dwords -> 2-way banks (free)

__device__ __forceinline__ half2v h2(unsigned u) {
  return __builtin_bit_cast(half2v, u);
}
__device__ __forceinline__ unsigned u32(half2v h) {
  return __builtin_bit_cast(unsigned, h);
}
__device__ __forceinline__ void tap(half2v a, half2v& mx, half2v& mn) {
  mx = __builtin_elementwise_max(mx, a);  // v_pk_max_f16
  mn = __builtin_elementwise_min(mn, a);  // v_pk_min_f16
}

__global__ __launch_bounds__(256, 3) void trop_kernel(
    const float* __restrict__ x, const float* __restrict__ w,
    const float* __restrict__ bias, float* __restrict__ out) {
  __shared__ _Float16 wt[64 * WSTRIDE];  // 37.9 KB: w transposed [f][k], f16
  __shared__ _Float16 xh[3 * 18 * 32];   // 3.4 KB: x rows f16 [ki][lcol][c]
  __shared__ uint4 red[2][2][2][64];     // 8 KB: [pair][mx/mn][half][f]

  const int i = blockIdx.x;   // output row 0..29
  const int b = blockIdx.y;   // batch 0..7
  const int z = blockIdx.z;   // col half: cols [z*16, z*16+16)
  const int tid = threadIdx.x;
  const int f = tid & 63;     // lane = filter
  const int W = __builtin_amdgcn_readfirstlane(tid >> 6);  // wave 0..3
  const int p = W & 1;        // col group of 8 within the z-half
  const int chalf = W >> 1;   // channel half: 0 -> c 0..15, 1 -> c 16..31
  const int j0 = z * 16 + p * 8;

  // ---- stage w transposed + f16: wave W covers k in [W*72, W*72+72) ----
  {
    const float* wp = w + f;
    const int kb = W * 72;
#pragma unroll
    for (int blk = 0; blk < 9; ++blk) {
      const int k0 = kb + blk * 8;
      half8v v;
#pragma unroll
      for (int u = 0; u < 8; ++u) v[u] = (_Float16)wp[(k0 + u) * 64];
      *(half8v*)&wt[f * WSTRIDE + k0] = v;  // 16 B aligned ds_write
    }
  }

  // ---- stage x rows i..i+2, global cols z*16 .. z*16+17 (clamped), f16 ----
  {
    const float* xb = x + (((size_t)b * 32 + i) * 32) * 32;
#pragma unroll
    for (int t = 0; t < 4; ++t) {
      const int g = tid + t * 256;
      if (g < 864) {               // 3 ki * 18 cols * 16 half2-pairs
        const int ki = g / 288;
        const int rem = g - ki * 288;
        const int col = rem >> 4;  // local col 0..17
        const int cp = rem & 15;   // half2 pair within channels
        int gcol = z * 16 + col;
        if (gcol > 31) gcol = 31;  // clamp halo (stores are guarded anyway)
        const float2 v = *(const float2*)(xb + ki * 1024 + gcol * 32 + cp * 2);
        half2v h;
        h.x = (_Float16)v.x;
        h.y = (_Float16)v.y;
        *(half2v*)&xh[(ki * 18 + col) * 32 + cp * 2] = h;
      }
    }
  }

  __syncthreads();

  const _Float16 NI = (_Float16)(-INFINITY), PI = (_Float16)INFINITY;
  half2v mxi, mni;
  mxi.x = NI; mxi.y = NI;
  mni.x = PI; mni.y = PI;
  half2v mx[8], mn[8];
#pragma unroll
  for (int t = 0; t < 8; ++t) {
    mx[t] = mxi;
    mn[t] = mni;
  }

#pragma clang loop unroll(disable)
  for (int kc = 0; kc < 6; ++kc) {
    const int ki = kc >> 1;                         // 0..2
    const int c8 = (chalf << 4) + ((kc & 1) << 3);  // this wave's 8 channels
    const _Float16* xrow = &xh[(ki * 18 + p * 8) * 32 + c8];
    const _Float16* wrow = &wt[f * WSTRIDE + ki * 96 + c8];

    // x: 10 cols x 8 ch, wave-uniform broadcast b128
    uint4 xa[10];
#pragma unroll
    for (int t = 0; t < 10; ++t) xa[t] = *(const uint4*)&xrow[t * 32];
    // w: lane f's own row, 3 kj, b128 each
    const uint4 wa0 = *(const uint4*)&wrow[0];
    const uint4 wa1 = *(const uint4*)&wrow[32];
    const uint4 wa2 = *(const uint4*)&wrow[64];

#define DOD(D)                                      \
  {                                                 \
    const half2v w0 = h2(wa0.D);                    \
    const half2v w1 = h2(wa1.D);                    \
    const half2v w2 = h2(wa2.D);                    \
    _Pragma("unroll") for (int t = 0; t < 8; ++t) { \
      tap(h2(xa[t].D) + w0, mx[t], mn[t]);          \
      tap(h2(xa[t + 1].D) + w1, mx[t], mn[t]);      \
      tap(h2(xa[t + 2].D) + w2, mx[t], mn[t]);      \
    }                                               \
  }
    DOD(x) DOD(y) DOD(z) DOD(w)
#undef DOD
  }

  // ---- cross-wave channel merge: chalf=1 publishes, chalf=0 combines ----
  if (chalf == 1) {
    uint4 t0, t1;
    t0.x = u32(mx[0]); t0.y = u32(mx[1]); t0.z = u32(mx[2]); t0.w = u32(mx[3]);
    t1.x = u32(mx[4]); t1.y = u32(mx[5]); t1.z = u32(mx[6]); t1.w = u32(mx[7]);
    red[p][0][0][f] = t0;
    red[p][0][1][f] = t1;
    t0.x = u32(mn[0]); t0.y = u32(mn[1]); t0.z = u32(mn[2]); t0.w = u32(mn[3]);
    t1.x = u32(mn[4]); t1.y = u32(mn[5]); t1.z = u32(mn[6]); t1.w = u32(mn[7]);
    red[p][1][0][f] = t0;
    red[p][1][1][f] = t1;
  }
  __syncthreads();
  if (chalf == 0) {
    const uint4 a0 = red[p][0][0][f], a1 = red[p][0][1][f];
    const uint4 b0 = red[p][1][0][f], b1 = red[p][1][1][f];
    mx[0] = __builtin_elementwise_max(mx[0], h2(a0.x));
    mx[1] = __builtin_elementwise_max(mx[1], h2(a0.y));
    mx[2] = __builtin_elementwise_max(mx[2], h2(a0.z));
    mx[3] = __builtin_elementwise_max(mx[3], h2(a0.w));
    mx[4] = __builtin_elementwise_max(mx[4], h2(a1.x));
    mx[5] = __builtin_elementwise_max(mx[5], h2(a1.y));
    mx[6] = __builtin_elementwise_max(mx[6], h2(a1.z));
    mx[7] = __builtin_elementwise_max(mx[7], h2(a1.w));
    mn[0] = __builtin_elementwise_min(mn[0], h2(b0.x));
    mn[1] = __builtin_elementwise_min(mn[1], h2(b0.y));
    mn[2] = __builtin_elementwise_min(mn[2], h2(b0.z));
    mn[3] = __builtin_elementwise_min(mn[3], h2(b0.w));
    mn[4] = __builtin_elementwise_min(mn[4], h2(b1.x));
    mn[5] = __builtin_elementwise_min(mn[5], h2(b1.y));
    mn[6] = __builtin_elementwise_min(mn[6], h2(b1.z));
    mn[7] = __builtin_elementwise_min(mn[7], h2(b1.w));

    // ---- epilogue: f32 subtract + bias; coalesced 256 B stores ----
    const float bv = bias[f];
    float* ob = out + (((size_t)b * 30 + i) * 30 + j0) * 64 + f;
#pragma unroll
    for (int t = 0; t < 8; ++t) {
      if (j0 + t < 30) {
        ob[t * 64] = fmaxf((float)mx[t].x, (float)mx[t].y) -
                     fminf((float)mn[t].x, (float)mn[t].y) + bv;
      }
    }
  }
}

extern "C" void kernel_launch(void* const* d_in, const int* in_sizes, int n_in,
                              void* d_out, int out_size, void* d_ws, size_t ws_size,
                              hipStream_t stream) {
  const float* x = (const float*)d_in[0];
  const float* w = (const float*)d_in[1];
  const float* bias = (const float*)d_in[2];
  float* out = (float*)d_out;
  dim3 grid(30, 8, 2);  // (row, batch, col-half) = 480 blocks, 4 waves each
  dim3 block(256);
  hipLaunchKernelGGL(trop_kernel, grid, block, 0, stream, x, w, bias, out);
}

// Round 2
// 66.181 us; speedup vs baseline: 1.0382x; 1.0382x over previous
//
#include <hip/hip_runtime.h>
#include <math.h>

// TropConv2D: out[b,i,j,f] = max_k(p[k]+w[k,f]) - min_k(p[k]+w[k,f]) + bias[f]
// k = (ki*3+kj)*32+c, 3x3 window, C=32, F=64.
// x: [8,32,32,32] f32, w: [288,64] f32, bias: [64] f32, out: [8,30,30,64] f32.
//
// R10 = R8 shell (grid (30,8)=240 blocks, block=1024, 16 waves/CU) with a
// 4-way channel split x 8-col waves to cut the binding LDS pipe:
//  - wave (cg, q) = 8 output cols x 64 filters x 8 channels.
//    Per ki: 10 x-broadcast b128 + 3 w b128 -> 39 reads/wave total vs R8's 54
//    (-28% on the ~10.4K cyc/CU LDS pipe), same 864 packed taps/thread.
//  - w staged tap-major: wt2[tap][q][f][8ch] f16 -> every LDS access
//    (stage write, w read, merge) is ideal lane-consecutive 16B.
//  - 3-partner merge buffer (48 KB) ALIASES dead wt2/xh after a barrier;
//    static LDS stays 48 KB (< 64 KB limit). VGPR ~95 -> 4 waves/SIMD.

typedef _Float16 half2v __attribute__((ext_vector_type(2)));

__device__ __forceinline__ half2v h2(unsigned u) {
  return __builtin_bit_cast(half2v, u);
}
__device__ __forceinline__ unsigned u32(half2v h) {
  return __builtin_bit_cast(unsigned, h);
}
__device__ __forceinline__ void tap1(half2v a, half2v& mx, half2v& mn) {
  mx = __builtin_elementwise_max(mx, a);  // v_pk_max_f16
  mn = __builtin_elementwise_min(mn, a);  // v_pk_min_f16
}

__global__ __launch_bounds__(1024) void trop_kernel(
    const float* __restrict__ x, const float* __restrict__ w,
    const float* __restrict__ bias, float* __restrict__ out) {
  // smem layout phase 1: wt2 [0,36864) + xh [36864,43008)
  // smem layout phase 2 (after barrier): red[3][4][4][64] uint4 = 49152 B
  __shared__ __align__(16) unsigned char smem[49152];
  _Float16* const wt2 = (_Float16*)smem;            // [tap][q][f][8ch]
  _Float16* const xh = (_Float16*)(smem + 36864);   // [ki][col][c]

  const int i = blockIdx.x;  // output row 0..29
  const int b = blockIdx.y;  // batch 0..7
  const int tid = threadIdx.x;
  const int f = tid & 63;    // lane = filter
  const int W = __builtin_amdgcn_readfirstlane(tid >> 6);  // wave 0..15
  const int cg = W & 3;      // col group: cols [cg*8, cg*8+8)
  const int q = W >> 2;      // channel quarter: c in [q*8, q*8+8)
  const int j0 = cg * 8;

  // ---- stage w -> wt2[tap][qq][ff][0..8] f16; items (tap,qq,ff) = 2304 ----
#pragma unroll
  for (int it = 0; it < 3; ++it) {
    const int idx = tid + it * 1024;
    if (idx < 2304) {
      const int ff = idx & 63;
      const int rest = idx >> 6;  // 0..35
      const int qq = rest & 3;
      const int tp = rest >> 2;   // 0..8
      const float* wp = w + (size_t)((tp * 32 + qq * 8) * 64 + ff);
      half2v h01, h23, h45, h67;
      h01.x = (_Float16)wp[0 * 64]; h01.y = (_Float16)wp[1 * 64];
      h23.x = (_Float16)wp[2 * 64]; h23.y = (_Float16)wp[3 * 64];
      h45.x = (_Float16)wp[4 * 64]; h45.y = (_Float16)wp[5 * 64];
      h67.x = (_Float16)wp[6 * 64]; h67.y = (_Float16)wp[7 * 64];
      uint4 pk;
      pk.x = u32(h01); pk.y = u32(h23); pk.z = u32(h45); pk.w = u32(h67);
      // lane-consecutive 16B: ideal ds_write_b128
      *(uint4*)&wt2[(size_t)((tp * 4 + qq) * 64 + ff) * 8] = pk;
    }
  }

  // ---- stage x rows i..i+2 as f16 [ki][col][c]: 1536 float2 loads ----
  {
    const float* xb = x + (((size_t)b * 32 + i) * 32) * 32;
#pragma unroll
    for (int t = 0; t < 2; ++t) {
      const int g = tid + t * 1024;
      if (g < 1536) {
        const int ki = g >> 9;
        const int rem = g & 511;
        const int col = rem >> 4;
        const int cp = rem & 15;
        const float2 v = *(const float2*)(xb + ki * 1024 + col * 32 + cp * 2);
        half2v h;
        h.x = (_Float16)v.x;
        h.y = (_Float16)v.y;
        *(half2v*)&xh[(ki * 32 + col) * 32 + cp * 2] = h;
      }
    }
  }

  __syncthreads();

  // clamped col offsets (halves) within one ki-row, incl. channel offset
  int cc[10];
#pragma unroll
  for (int u = 0; u < 10; ++u) {
    const int col = (j0 + u < 32) ? (j0 + u) : 31;
    cc[u] = col * 32 + q * 8;
  }

  const _Float16 NI = (_Float16)(-INFINITY), PI = (_Float16)INFINITY;
  half2v mx[8], mn[8];
#pragma unroll
  for (int t = 0; t < 8; ++t) {
    mx[t].x = NI; mx[t].y = NI;
    mn[t].x = PI; mn[t].y = PI;
  }

#pragma clang loop unroll(disable)
  for (int ki = 0; ki < 3; ++ki) {
    const _Float16* xr = &xh[ki * 1024];
    const _Float16* wr = &wt2[(size_t)((ki * 12 + q) * 64 + f) * 8];
    // x: 10 cols x 8 ch, wave-uniform broadcast b128 (free)
    uint4 xa[10];
#pragma unroll
    for (int u = 0; u < 10; ++u) xa[u] = *(const uint4*)&xr[cc[u]];
    // w: lane f's 8 channels for kj=0,1,2 (lane-consecutive 16B: ideal)
    const uint4 wk0 = *(const uint4*)&wr[0];
    const uint4 wk1 = *(const uint4*)&wr[4 * 64 * 8];
    const uint4 wk2 = *(const uint4*)&wr[8 * 64 * 8];

#define DOD(D)                                      \
  {                                                 \
    const half2v w0 = h2(wk0.D);                    \
    const half2v w1 = h2(wk1.D);                    \
    const half2v w2 = h2(wk2.D);                    \
    _Pragma("unroll") for (int t = 0; t < 8; ++t) { \
      tap1(h2(xa[t].D) + w0, mx[t], mn[t]);         \
      tap1(h2(xa[t + 1].D) + w1, mx[t], mn[t]);     \
      tap1(h2(xa[t + 2].D) + w2, mx[t], mn[t]);     \
    }                                               \
  }
    DOD(x) DOD(y) DOD(z) DOD(w)
#undef DOD
  }

  // wt2/xh are dead from here; re-use smem as the merge buffer
  __syncthreads();
  uint4(*red)[4][4][64] = (uint4(*)[4][4][64])smem;  // [q-1][cg][word][f]

  if (q > 0) {
    uint4 a;
    a.x = u32(mx[0]); a.y = u32(mx[1]); a.z = u32(mx[2]); a.w = u32(mx[3]);
    red[q - 1][cg][0][f] = a;
    a.x = u32(mx[4]); a.y = u32(mx[5]); a.z = u32(mx[6]); a.w = u32(mx[7]);
    red[q - 1][cg][1][f] = a;
    a.x = u32(mn[0]); a.y = u32(mn[1]); a.z = u32(mn[2]); a.w = u32(mn[3]);
    red[q - 1][cg][2][f] = a;
    a.x = u32(mn[4]); a.y = u32(mn[5]); a.z = u32(mn[6]); a.w = u32(mn[7]);
    red[q - 1][cg][3][f] = a;
  }
  __syncthreads();

  if (q == 0) {
#pragma unroll
    for (int qq = 0; qq < 3; ++qq) {
      const uint4 a0 = red[qq][cg][0][f];
      const uint4 a1 = red[qq][cg][1][f];
      const uint4 b0 = red[qq][cg][2][f];
      const uint4 b1 = red[qq][cg][3][f];
      mx[0] = __builtin_elementwise_max(mx[0], h2(a0.x));
      mx[1] = __builtin_elementwise_max(mx[1], h2(a0.y));
      mx[2] = __builtin_elementwise_max(mx[2], h2(a0.z));
      mx[3] = __builtin_elementwise_max(mx[3], h2(a0.w));
      mx[4] = __builtin_elementwise_max(mx[4], h2(a1.x));
      mx[5] = __builtin_elementwise_max(mx[5], h2(a1.y));
      mx[6] = __builtin_elementwise_max(mx[6], h2(a1.z));
      mx[7] = __builtin_elementwise_max(mx[7], h2(a1.w));
      mn[0] = __builtin_elementwise_min(mn[0], h2(b0.x));
      mn[1] = __builtin_elementwise_min(mn[1], h2(b0.y));
      mn[2] = __builtin_elementwise_min(mn[2], h2(b0.z));
      mn[3] = __builtin_elementwise_min(mn[3], h2(b0.w));
      mn[4] = __builtin_elementwise_min(mn[4], h2(b1.x));
      mn[5] = __builtin_elementwise_min(mn[5], h2(b1.y));
      mn[6] = __builtin_elementwise_min(mn[6], h2(b1.z));
      mn[7] = __builtin_elementwise_min(mn[7], h2(b1.w));
    }

    // ---- epilogue: f32 subtract + bias; coalesced 256 B stores ----
    const float bv = bias[f];
    float* ob = out + (((size_t)b * 30 + i) * 30 + j0) * 64 + f;
#pragma unroll
    for (int t = 0; t < 8; ++t) {
      if (j0 + t < 30) {
        ob[t * 64] = fmaxf((float)mx[t].x, (float)mx[t].y) -
                     fminf((float)mn[t].x, (float)mn[t].y) + bv;
      }
    }
  }
}

extern "C" void kernel_launch(void* const* d_in, const int* in_sizes, int n_in,
                              void* d_out, int out_size, void* d_ws, size_t ws_size,
                              hipStream_t stream) {
  const float* x = (const float*)d_in[0];
  const float* w = (const float*)d_in[1];
  const float* bias = (const float*)d_in[2];
  float* out = (float*)d_out;
  dim3 grid(30, 8);  // (row, batch) = 240 blocks, 16 waves each
  dim3 block(1024);
  hipLaunchKernelGGL(trop_kernel, grid, block, 0, stream, x, w, bias, out);
}